// Round 12
// baseline (81.231 us; speedup 1.0000x reference)
//
#include <hip/hip_runtime.h>

#define K_SPARSE 64
#define COLS     4096
#define NTHREADS 256
#define WAVES    4                   // rows per block: one row per wave
#define EPT      64                  // elements per lane (COLS / 64 lanes)
#define VPT      (EPT / 4)           // 16 float4 loads per lane
#define FAST_CAP 512                 // per-wave candidate cap
#define LPAD     (FAST_CAP + 8)      // + pad for b128 tail reads

typedef float    nfloat4 __attribute__((ext_vector_type(4)));
typedef unsigned nuint4  __attribute__((ext_vector_type(4)));

// Order-preserving fp32 -> uint32 mapping (ascending float order == ascending uint order)
__device__ __forceinline__ unsigned mapf(unsigned b) {
    return (b & 0x80000000u) ? ~b : (b | 0x80000000u);
}
__device__ __forceinline__ float unmapf(unsigned u) {
    unsigned b = (u & 0x80000000u) ? (u ^ 0x80000000u) : ~u;
    return __uint_as_float(b);
}

// One row per WAVE: zero __syncthreads in the whole kernel. All cross-lane
// communication is wave-synchronous (shfl/ballot); LDS holds only the
// per-wave candidate list, read via broadcast ds_read_b128.
__global__ __launch_bounds__(NTHREADS)
void ksparse_wave(const float* __restrict__ x, float* __restrict__ out, int rows)
{
    const int t    = threadIdx.x;
    const int lane = t & 63;
    const int w    = t >> 6;
    const int row  = blockIdx.x * WAVES + w;
    if (row >= rows) return;

    __shared__ __align__(16) unsigned list[WAVES][LPAD];
    unsigned* const lw = list[w];

    const float4* __restrict__ xrow =
        reinterpret_cast<const float4*>(x) + (size_t)row * (COLS / 4);
    nfloat4* __restrict__ orow =
        reinterpret_cast<nfloat4*>(out) + (size_t)row * (COLS / 4);

    // Whole row into registers as order-mapped uints (floats reconstructed
    // bit-exactly at store time).
    unsigned u[EPT];
#pragma unroll
    for (int i = 0; i < VPT; ++i) {
        float4 v = xrow[lane + i * 64];
        u[i * 4 + 0] = mapf(__float_as_uint(v.x));
        u[i * 4 + 1] = mapf(__float_as_uint(v.y));
        u[i * 4 + 2] = mapf(__float_as_uint(v.z));
        u[i * 4 + 3] = mapf(__float_as_uint(v.w));
    }

    // --- Phase 1: threshold rungs (wave-local, no barriers).
    // mapf(1.9f)=0xBFF33333 (E[c]~118 on N(0,1)); mapf(1.5f)=0xBFC00000 (E~274).
    // Rungs affect only speed; exactness comes from the select / fallback.
    unsigned uT = 0, cnt = 0, base = 0, c = 0;
#pragma unroll
    for (int r = 0; r < 2; ++r) {
        uT = (r == 0) ? 0xBFF33333u : 0xBFC00000u;
        cnt = 0;
#pragma unroll
        for (int i = 0; i < EPT; ++i) cnt += (u[i] > uT) ? 1u : 0u;

        unsigned s = cnt;                       // wave inclusive prefix scan
#pragma unroll
        for (int off = 1; off < 64; off <<= 1) {
            unsigned v = __shfl_up(s, off, 64);
            if (lane >= off) s += v;
        }
        c    = __shfl(s, 63, 64);               // wave total (uniform)
        base = s - cnt;                         // exclusive prefix
        if (c >= K_SPARSE + 1) break;
    }

    unsigned ukth;
    if (c >= K_SPARSE + 1 && c <= FAST_CAP) {
        // --- Phase 2: compact candidates to this wave's LDS list. No atomics.
        unsigned pos = base;
#pragma unroll
        for (int i = 0; i < EPT; ++i) {
            if (u[i] > uT) lw[pos++] = u[i];
        }
        if (lane < 8) lw[c + lane] = 0u;        // pad for b128 tail reads
        // Wave-synchronous LDS: writes above, reads below, same wave ->
        // program order + compiler lgkmcnt suffice; no barrier.

        // --- Phase 3: exact tie-aware rank-K select among c candidates.
        // v* is the unique value with g(v*) <= K < g(v*)+e(v*).
        const int nq = (int)((c + 3) >> 2);
        const nuint4* lv = reinterpret_cast<const nuint4*>(lw);
        bool found = false;
        unsigned vmatch = 0u;
        for (int j = lane; j < (int)c; j += 64) {
            const unsigned vj = lw[j];
            unsigned g = 0, e = 0;
            for (int q = 0; q < nq; ++q) {
                const nuint4 ql = lv[q];        // broadcast read (all lanes same addr)
                g += (ql.x > vj) + (ql.y > vj) + (ql.z > vj) + (ql.w > vj);
                e += (ql.x == vj) + (ql.y == vj) + (ql.z == vj) + (ql.w == vj);
            }
            if (g <= (unsigned)K_SPARSE && (unsigned)K_SPARSE < g + e) {
                found = true; vmatch = vj;
            }
        }
        const unsigned long long m = __ballot(found);   // >=1 lane matches
        const int src = __ffsll(m) - 1;
        ukth = __shfl(vmatch, src, 64);
    } else {
        // --- Fallback (exact for any input; ~never taken on N(0,1)):
        // bitwise search for largest v with |{u >= v}| >= K+1  == mapped kth.
        unsigned prefix = 0u;
        for (int b = 31; b >= 0; --b) {
            const unsigned trial = prefix | (1u << b);
            unsigned c2 = 0;
#pragma unroll
            for (int i = 0; i < EPT; ++i) c2 += (u[i] >= trial) ? 1u : 0u;
#pragma unroll
            for (int off = 32; off >= 1; off >>= 1)
                c2 += __shfl_xor(c2, off, 64);  // butterfly: uniform across wave
            if (c2 >= K_SPARSE + 1) prefix = trial;
        }
        ukth = prefix;
    }

    // --- Phase 4: masked nt-store (mapped compare == float compare for
    // non-NaN; value reconstructed bit-exactly).
#pragma unroll
    for (int i = 0; i < VPT; ++i) {
        nfloat4 o;
        o.x = (u[i * 4 + 0] > ukth) ? unmapf(u[i * 4 + 0]) : 0.0f;
        o.y = (u[i * 4 + 1] > ukth) ? unmapf(u[i * 4 + 1]) : 0.0f;
        o.z = (u[i * 4 + 2] > ukth) ? unmapf(u[i * 4 + 2]) : 0.0f;
        o.w = (u[i * 4 + 3] > ukth) ? unmapf(u[i * 4 + 3]) : 0.0f;
        __builtin_nontemporal_store(o, &orow[lane + i * 64]);
    }
}

extern "C" void kernel_launch(void* const* d_in, const int* in_sizes, int n_in,
                              void* d_out, int out_size, void* d_ws, size_t ws_size,
                              hipStream_t stream) {
    const float* x = (const float*)d_in[0];
    float* out = (float*)d_out;
    const int rows = in_sizes[0] / COLS;
    const int blocks = (rows + WAVES - 1) / WAVES;
    ksparse_wave<<<blocks, NTHREADS, 0, stream>>>(x, out, rows);
}

// Round 13
// 71.736 us; speedup vs baseline: 1.1324x; 1.1324x over previous
//
#include <hip/hip_runtime.h>

#define K_SPARSE 64
#define COLS     4096
#define NTHREADS 256
#define EPT      (COLS / NTHREADS)   // 16 elements per thread
#define VPT      (EPT / 4)           // 4 float4 loads per thread
#define FAST_CAP 1024                // fast-path candidate cap
#define LIST_CAP (FAST_CAP + 8)      // + pad for b128 tail reads

typedef float    nfloat4 __attribute__((ext_vector_type(4)));
typedef unsigned nuint4  __attribute__((ext_vector_type(4)));

// Order-preserving fp32 -> uint32 mapping (ascending float order == ascending uint order)
__device__ __forceinline__ unsigned mapf(unsigned b) {
    return (b & 0x80000000u) ? ~b : (b | 0x80000000u);
}
__device__ __forceinline__ float unmapf(unsigned u) {
    unsigned b = (u & 0x80000000u) ? (u ^ 0x80000000u) : ~u;
    return __uint_as_float(b);
}

__global__ __launch_bounds__(NTHREADS)
void ksparse_select(const float* __restrict__ x, float* __restrict__ out, int rows)
{
    const int row = blockIdx.x;
    if (row >= rows) return;
    const int t    = threadIdx.x;
    const int lane = t & 63;
    const int w    = t >> 6;          // wave id 0..3

    __shared__ __align__(16) unsigned list[LIST_CAP];
    __shared__ unsigned wtot[4];
    __shared__ unsigned s_kth;

    const float4* __restrict__ xrow =
        reinterpret_cast<const float4*>(x) + (size_t)row * (COLS / 4);
    nfloat4* __restrict__ orow =
        reinterpret_cast<nfloat4*>(out) + (size_t)row * (COLS / 4);

    // Row lives in registers ONLY as mapped uints (u[16] ~ 16 VGPR demand;
    // floats reconstructed bit-exactly at store). Keeps us under the
    // allocator's pick -> no scratch spill (R7/R11/R12 lesson).
    unsigned u[EPT];
#pragma unroll
    for (int i = 0; i < VPT; ++i) {
        float4 v = xrow[t + i * NTHREADS];
        u[i * 4 + 0] = mapf(__float_as_uint(v.x));
        u[i * 4 + 1] = mapf(__float_as_uint(v.y));
        u[i * 4 + 2] = mapf(__float_as_uint(v.z));
        u[i * 4 + 3] = mapf(__float_as_uint(v.w));
    }

    // --- Phase 1: threshold rungs. mapf(1.9f)=0xBFF33333 (E[c]~118 on N(0,1)),
    // mapf(0.9f)=0xBF666666 (E[c]~754). Rungs affect speed only; exactness
    // comes from the select / the fallback.
    unsigned uT = 0, cnt = 0, base = 0, c = 0;
#pragma unroll
    for (int r = 0; r < 2; ++r) {
        uT = (r == 0) ? 0xBFF33333u : 0xBF666666u;
        cnt = 0;
#pragma unroll
        for (int i = 0; i < EPT; ++i) cnt += (u[i] > uT) ? 1u : 0u;

        unsigned s = cnt;                    // wave inclusive prefix scan
#pragma unroll
        for (int off = 1; off < 64; off <<= 1) {
            unsigned v = __shfl_up(s, off, 64);
            if (lane >= off) s += v;
        }
        if (lane == 63) wtot[w] = s;
        __syncthreads();                     // B1: wtot visible
        const unsigned c0 = wtot[0], c1 = wtot[1], c2 = wtot[2], c3 = wtot[3];
        c = c0 + c1 + c2 + c3;
        if (c >= K_SPARSE + 1 || r == 1) {
            base = (w > 0 ? c0 : 0u) + (w > 1 ? c1 : 0u) + (w > 2 ? c2 : 0u)
                 + s - cnt;                  // block-wide exclusive prefix
            break;
        }
        __syncthreads();                     // B1b: wtot consumed before rewrite
    }

    unsigned ukth;
    if (c >= K_SPARSE + 1 && c <= FAST_CAP) {
        // --- Phase 2: compact candidates (u > uT) to LDS. No atomics.
        unsigned pos = base;
#pragma unroll
        for (int i = 0; i < EPT; ++i) {
            if (u[i] > uT) list[pos++] = u[i];
        }
        if (t < 8) list[c + t] = 0u;         // pad so b128 tail reads are neutral
        __syncthreads();                     // B2: list complete

        // --- Phase 3: exact tie-aware rank-K select among c candidates.
        // v* unique with g(v*) <= K < g(v*)+e(v*), matching sorted[n-1-K].
        const int nq = (int)((c + 3) >> 2);
        const nuint4* listv = reinterpret_cast<const nuint4*>(list);
        for (int j = t; j < (int)c; j += NTHREADS) {
            const unsigned vj = list[j];
            unsigned g = 0, e = 0;
            for (int q = 0; q < nq; ++q) {
                const nuint4 ql = listv[q];  // broadcast read: all lanes same addr
                g += (ql.x > vj) + (ql.y > vj) + (ql.z > vj) + (ql.w > vj);
                e += (ql.x == vj) + (ql.y == vj) + (ql.z == vj) + (ql.w == vj);
            }
            if (g <= (unsigned)K_SPARSE && (unsigned)K_SPARSE < g + e)
                s_kth = vj;                  // unique value; benign same-value race
        }
        __syncthreads();                     // B3: s_kth visible
        ukth = s_kth;
    } else {
        // --- Fallback (exact for any input; ~never taken on N(0,1) data):
        // bitwise search for the largest v with |{u >= v}| >= K+1 == mapped kth.
        unsigned prefix = 0u;
        for (int b = 31; b >= 0; --b) {
            const unsigned trial = prefix | (1u << b);
            unsigned c2 = 0;
#pragma unroll
            for (int i = 0; i < EPT; ++i) c2 += (u[i] >= trial) ? 1u : 0u;
#pragma unroll
            for (int off = 32; off >= 1; off >>= 1)
                c2 += __shfl_xor(c2, off, 64);       // wave butterfly reduce
            if (lane == 0) wtot[w] = c2;
            __syncthreads();
            const unsigned tot = wtot[0] + wtot[1] + wtot[2] + wtot[3];
            if (tot >= K_SPARSE + 1) prefix = trial;
            __syncthreads();                 // protect wtot before next bit
        }
        ukth = prefix;                       // identical in every thread
    }

    // --- Phase 4: masked nt-store. Mapped-domain compare == float compare
    // (strictly monotone on non-NaN); value reconstructed bit-exactly.
#pragma unroll
    for (int i = 0; i < VPT; ++i) {
        nfloat4 o;
        o.x = (u[i * 4 + 0] > ukth) ? unmapf(u[i * 4 + 0]) : 0.0f;
        o.y = (u[i * 4 + 1] > ukth) ? unmapf(u[i * 4 + 1]) : 0.0f;
        o.z = (u[i * 4 + 2] > ukth) ? unmapf(u[i * 4 + 2]) : 0.0f;
        o.w = (u[i * 4 + 3] > ukth) ? unmapf(u[i * 4 + 3]) : 0.0f;
        __builtin_nontemporal_store(o, &orow[t + i * NTHREADS]);
    }
}

extern "C" void kernel_launch(void* const* d_in, const int* in_sizes, int n_in,
                              void* d_out, int out_size, void* d_ws, size_t ws_size,
                              hipStream_t stream) {
    const float* x = (const float*)d_in[0];
    float* out = (float*)d_out;
    const int rows = in_sizes[0] / COLS;
    ksparse_select<<<rows, NTHREADS, 0, stream>>>(x, out, rows);
}